// Round 1
// baseline (131.092 us; speedup 1.0000x reference)
//
#include <hip/hip_runtime.h>

// KDE entropy loss, MI355X/gfx950 — fp8 fused GEMM, symmetric pairs once,
// wrapped-diagonal mapping. R8: 2-phase K-split per J-tile with counted
// vmcnt (T3+T4: loads span barriers, never drain to 0 in-loop), raw
// s_barrier, s_setprio around MFMA clusters (T5), colsum atomics moved from
// global (vmcnt-ack on every iter's barrier drain) to LDS (flushed once at
// end), packed f32 epilogue adds.
// ws: [0,4MiB) Xn fp8 [16384][256]; [4MiB,+64KiB) density f32; then ticket u32.

#define NROWS 16384
#define KDIM 256            // bytes per fp8 row
#define NTILE 128
#define NT (NROWS / NTILE)  // 128 tile rows
#define NSTRIP 4
#define TOTAL_BLOCKS (NT * NSTRIP)  // 512 blocks of 512 thr = exactly 2 per CU

// sqrt(5 * log2(e)): folded into both operands -> sim scaled by 5*log2(e),
// so kernel = exp2(sim_scaled) = exp(5*sim).
#define SQRT_KLOG2E 2.68579577857f

#define CS_LDS_FLOATS (17 * NTILE)               // max nt = 17
#define SMEM_BYTES (65536 + CS_LDS_FLOATS * 4)   // 74240 B; 2 blocks/CU fits 160K

typedef int i32x4_t __attribute__((ext_vector_type(4)));
typedef int i32x8_t __attribute__((ext_vector_type(8)));
typedef float f32x2_t __attribute__((ext_vector_type(2)));
typedef float f32x16_t __attribute__((ext_vector_type(16)));
typedef __attribute__((address_space(1))) const void global_cvoid_t;
typedef __attribute__((address_space(3))) void lds_void_t;

#if __has_builtin(__builtin_amdgcn_exp2f)
#define EXP2(x) __builtin_amdgcn_exp2f(x)
#else
#define EXP2(x) exp2f(x)
#endif

// Counted vmcnt wait: asm memory clobber pins all memory ops (ds_read,
// global_load_lds) on their program-order side of the wait.
#define WAITVM(n) asm volatile("s_waitcnt vmcnt(" #n ")" ::: "memory")

union frag8 { i32x8_t v8; i32x4_t v4[2]; };

// One wave per row: sqrt(5log2e)/max(||x||,eps), fp8 e4m3 out; zero density+ticket.
__global__ __launch_bounds__(256)
void kde_normalize(const float* __restrict__ X, unsigned int* __restrict__ Xn8,
                   float* __restrict__ density, unsigned int* __restrict__ ticket) {
  const int wave = threadIdx.x >> 6;
  const int lane = threadIdx.x & 63;
  const int row = blockIdx.x * 4 + wave;
  const float4 v = ((const float4*)(X + (size_t)row * KDIM))[lane];
  float ss = v.x * v.x + v.y * v.y + v.z * v.z + v.w * v.w;
  ss += __shfl_xor(ss, 1);
  ss += __shfl_xor(ss, 2);
  ss += __shfl_xor(ss, 4);
  ss += __shfl_xor(ss, 8);
  ss += __shfl_xor(ss, 16);
  ss += __shfl_xor(ss, 32);
  const float scale = SQRT_KLOG2E / fmaxf(sqrtf(ss), 1e-12f);
  int p = 0;
  p = __builtin_amdgcn_cvt_pk_fp8_f32(v.x * scale, v.y * scale, p, false);
  p = __builtin_amdgcn_cvt_pk_fp8_f32(v.z * scale, v.w * scale, p, true);
  Xn8[(size_t)row * 64 + lane] = (unsigned int)p;
  if (threadIdx.x < 4) density[blockIdx.x * 4 + threadIdx.x] = 0.0f;
  if (blockIdx.x == 0 && threadIdx.x == 0) *ticket = 0u;
}

// Block (bi, s): row tile bi; J = (bi+t) mod 128 for t in [s*16, s*16+16)
// (+ t=64 for s==0, bi<64 — dispatched first so the 17-iter blocks start
// earliest). Each unordered tile pair once. 8 waves 4x2 over 128x128; wave =
// 32x64 = 1x2 MFMA 32x32x64 fp8 (scale=1 -> exact e4m3). A in registers
// (32 VGPR); B double-buffers in 64 KB LDS.
//
// Per J-tile: two phases (kb 0-1, kb 2-3). Phase P of iter k issues the
// 2 global_load_lds for half P of tile k+1, computes half P of tile k, then
// s_waitcnt vmcnt(2) + s_barrier. vmcnt ledger (in-order completion):
//   end of A(k): outstanding = {h1(k) x2 [from B(k-1)], h0(k+1) x2} ->
//     vmcnt(2) => h1(k) landed => B(k) may read it.
//   end of B(k): outstanding = {h0(k+1) x2, h1(k+1) x2} ->
//     vmcnt(2) => h0(k+1) landed => A(k+1) may read it.
// Last iter stages nothing -> vmcnt(0) (uniform branch). Stage writes target
// the buffer last read >=2 barriers earlier. No global vmem ops in-loop:
// colsum goes to cs_lds via ds atomics (lgkm path), flushed after the loop.
__global__ __launch_bounds__(512, 4)
void kde_gemm(const unsigned char* __restrict__ Xn8, float* __restrict__ density,
              unsigned int* __restrict__ ticket, float* __restrict__ out) {
  extern __shared__ char smem[];
  char* buf0 = smem;           // 32 KB
  char* buf1 = smem + 32768;   // 32 KB
  float* cs_lds = (float*)(smem + 65536);  // [nt][128] colsum accumulators

  const int tid = threadIdx.x;
  const int wave = tid >> 6;   // 0..7
  const int lane = tid & 63;
  const int wr = wave >> 1;    // row quarter 0..3 (32 rows each)
  const int wc = wave & 1;     // col half 0..1 (64 cols each)
  const int m32 = lane & 31;
  const int h = lane >> 5;
  const int bi = blockIdx.x;
  const int s = blockIdx.y;
  const int t0 = s * 16;
  const int nt = (s == 0 && bi < NT / 2) ? 17 : 16;
  const char* Xb = (const char*)Xn8;

  // Chunk c = rt*8 + kb*2 + hh: lane holds M[rt*32+m32][kb*64+h*32+hh*16 ..+15]
#define STAGE(base_row, dst)                                                      \
  for (int c = wave; c < 32; c += 8) {                                            \
    const int rt = c >> 3, kb = (c >> 1) & 3, hh = c & 1;                         \
    const size_t gofs =                                                           \
        (size_t)((base_row) + rt * 32 + m32) * KDIM + kb * 64 + h * 32 + hh * 16; \
    __builtin_amdgcn_global_load_lds((global_cvoid_t*)(Xb + gofs),                \
                                     (lds_void_t*)((dst) + c * 1024), 16, 0, 0);  \
  }

  // Half hf (kb in {2hf, 2hf+1}): 2 loads per wave, all 16 chunks covered by
  // the 8 waves (wave -> rt = wave>>1, kb = 2*hf + (wave&1), hh = 0,1).
#define STAGE_HALF(base_row, dst, hf)                                             \
  {                                                                               \
    const int rt_ = wave >> 1;                                                    \
    const int kb_ = 2 * (hf) + (wave & 1);                                        \
    const size_t g0_ =                                                            \
        (size_t)((base_row) + rt_ * 32 + m32) * KDIM + kb_ * 64 + h * 32;         \
    __builtin_amdgcn_global_load_lds(                                             \
        (global_cvoid_t*)(Xb + g0_),                                              \
        (lds_void_t*)((dst) + (rt_ * 8 + kb_ * 2) * 1024), 16, 0, 0);             \
    __builtin_amdgcn_global_load_lds(                                             \
        (global_cvoid_t*)(Xb + g0_ + 16),                                         \
        (lds_void_t*)((dst) + (rt_ * 8 + kb_ * 2 + 1) * 1024), 16, 0, 0);         \
  }

  // Zero colsum accumulators (visible after the first __syncthreads).
  for (int i = tid; i < nt * NTILE; i += 512) cs_lds[i] = 0.0f;

  STAGE(bi * NTILE, buf0);                      // A tile -> buf0
  STAGE(((bi + t0) & (NT - 1)) * NTILE, buf1);  // B(0)   -> buf1
  __syncthreads();  // full drain: both tiles + cs_lds zeros visible

  // A fragments -> registers: this wave's 32 rows, full K (32 VGPRs).
  frag8 areg[4];
#pragma unroll
  for (int kb = 0; kb < 4; kb++) {
    const char* pa = buf0 + (wr * 8 + kb * 2) * 1024 + lane * 16;
    areg[kb].v4[0] = *(const i32x4_t*)pa;
    areg[kb].v4[1] = *(const i32x4_t*)(pa + 1024);
  }
  __syncthreads();  // all waves done reading A from buf0

  f32x2_t rs2[8];
#pragma unroll
  for (int r = 0; r < 8; r++) rs2[r] = (f32x2_t)0.0f;

  for (int k = 0; k < nt; ++k) {
    const int t = (k == 16) ? 64 : (t0 + k);
    char* rbuf = (k & 1) ? buf0 : buf1;  // B(k): confirmed landed
    char* sbuf = (k & 1) ? buf1 : buf0;  // last read at iter k-1 (>=2 barriers)
    const bool pre = (k + 1 < nt);
    const int tn = (k + 1 == 16) ? 64 : (t0 + k + 1);
    const int Jn = (bi + tn) & (NT - 1);

    f32x16_t acc[2];
#pragma unroll
    for (int j = 0; j < 2; j++) acc[j] = (f32x16_t)0.0f;

    // ---------------- phase A: kb 0,1 ----------------
    if (pre) STAGE_HALF(Jn * NTILE, sbuf, 0);
#pragma unroll
    for (int kbl = 0; kbl < 2; ++kbl) {
      frag8 bf[2];
#pragma unroll
      for (int j = 0; j < 2; j++) {
        const char* pb = rbuf + ((wc * 2 + j) * 8 + kbl * 2) * 1024 + lane * 16;
        bf[j].v4[0] = *(const i32x4_t*)pb;
        bf[j].v4[1] = *(const i32x4_t*)(pb + 1024);
      }
      __builtin_amdgcn_s_setprio(1);
#pragma unroll
      for (int j = 0; j < 2; j++)
        acc[j] = __builtin_amdgcn_mfma_scale_f32_32x32x64_f8f6f4(
            areg[kbl].v8, bf[j].v8, acc[j], 0, 0, 0, 127, 0, 127);
      __builtin_amdgcn_s_setprio(0);
    }
    if (pre) { WAITVM(2); } else { WAITVM(0); }  // h1(k) landed (mine)
    __builtin_amdgcn_s_barrier();                // h1(k) landed (everyone's)

    // ---------------- phase B: kb 2,3 ----------------
    if (pre) STAGE_HALF(Jn * NTILE, sbuf, 1);
#pragma unroll
    for (int kbl = 0; kbl < 2; ++kbl) {
      frag8 bf[2];
#pragma unroll
      for (int j = 0; j < 2; j++) {
        const char* pb =
            rbuf + ((wc * 2 + j) * 8 + (2 + kbl) * 2) * 1024 + lane * 16;
        bf[j].v4[0] = *(const i32x4_t*)pb;
        bf[j].v4[1] = *(const i32x4_t*)(pb + 1024);
      }
      __builtin_amdgcn_s_setprio(1);
#pragma unroll
      for (int j = 0; j < 2; j++)
        acc[j] = __builtin_amdgcn_mfma_scale_f32_32x32x64_f8f6f4(
            areg[2 + kbl].v8, bf[j].v8, acc[j], 0, 0, 0, 127, 0, 127);
      __builtin_amdgcn_s_setprio(0);
    }

    // Epilogue: e = exp2(sim_scaled) = exp(5*sim). Rowsums in regs across k;
    // colsums into LDS (ds atomics: lgkm path, not vmcnt).
    // C/D: col = m32, row = (r&3) + 8*(r>>2) + 4*h.
#pragma unroll
    for (int j = 0; j < 2; j++) {
      f32x2_t csj = (f32x2_t)0.0f;
#pragma unroll
      for (int r2 = 0; r2 < 8; r2++) {
        f32x2_t e;
        e.x = EXP2(acc[j][2 * r2]);
        e.y = EXP2(acc[j][2 * r2 + 1]);
        rs2[r2] += e;  // v_pk_add_f32
        csj += e;
      }
      if (t != 0) {  // diagonal tile (t=0): rowsum only
        float v = csj.x + csj.y;
        v += __shfl_xor(v, 32);  // combine h halves -> 32 rows
        if (h == 0)
          atomicAdd(&cs_lds[k * NTILE + wc * 64 + j * 32 + m32], v);
      }
    }

    if (pre) { WAITVM(2); } else { WAITVM(0); }  // h0(k+1) landed (mine)
    __builtin_amdgcn_s_barrier();                // h0(k+1) landed (everyone's)
  }

  // Row epilogue: reduce over 32 cols (m32), scatter; 2 atomics/row (wc=0,1).
#pragma unroll
  for (int r = 0; r < 16; r++) {
    float v = rs2[r >> 1][r & 1];
    v += __shfl_xor(v, 1);
    v += __shfl_xor(v, 2);
    v += __shfl_xor(v, 4);
    v += __shfl_xor(v, 8);
    v += __shfl_xor(v, 16);
    if (m32 == 0) {
      const int row = bi * NTILE + wr * 32 + (r & 3) + 8 * (r >> 2) + 4 * h;
      atomicAdd(&density[row], v);
    }
  }

  // Colsum flush: lgkm drained by __syncthreads -> all waves' ds_adds done.
  __syncthreads();
  for (int idx = tid; idx < nt * NTILE; idx += 512) {
    const int kk = idx >> 7;
    const int tt = (kk == 16) ? 64 : (t0 + kk);
    if (tt == 0) continue;  // diagonal tile: never written
    const int JJ = (bi + tt) & (NT - 1);
    atomicAdd(&density[JJ * NTILE + (idx & 127)], cs_lds[idx]);
  }
#undef STAGE
#undef STAGE_HALF

  // Ticket: last finished block computes the entropy (saves 2 launches).
  __syncthreads();  // all atomics issued & drained (vmcnt(0) at barrier)
  if (tid == 0) {
    __threadfence();
    ((volatile unsigned int*)smem)[0] = atomicAdd(ticket, 1u);
  }
  __syncthreads();
  if (((volatile unsigned int*)smem)[0] == TOTAL_BLOCKS - 1) {
    __threadfence();
    float ssum = 0.0f;
    for (int i = tid; i < NROWS; i += 512) {
      const float d = __hip_atomic_load(&density[i], __ATOMIC_RELAXED,
                                        __HIP_MEMORY_SCOPE_AGENT);
      ssum += logf(d + 1e-9f);
    }
    ssum += __shfl_xor(ssum, 1);
    ssum += __shfl_xor(ssum, 2);
    ssum += __shfl_xor(ssum, 4);
    ssum += __shfl_xor(ssum, 8);
    ssum += __shfl_xor(ssum, 16);
    ssum += __shfl_xor(ssum, 32);
    float* red = ((float*)smem) + 16;
    if (lane == 0) red[wave] = ssum;
    __syncthreads();
    if (tid == 0) {
      float tot = 0.0f;
      for (int w = 0; w < 8; w++) tot += red[w];
      out[0] = -tot / (float)NROWS;
    }
  }
}

extern "C" void kernel_launch(void* const* d_in, const int* in_sizes, int n_in,
                              void* d_out, int out_size, void* d_ws, size_t ws_size,
                              hipStream_t stream) {
  const float* X = (const float*)d_in[0];
  float* out = (float*)d_out;
  char* ws = (char*)d_ws;
  unsigned int* Xn8 = (unsigned int*)ws;
  float* density = (float*)(ws + (size_t)NROWS * KDIM);
  unsigned int* ticket = (unsigned int*)(density + NROWS);

  hipFuncSetAttribute((const void*)kde_gemm,
                      hipFuncAttributeMaxDynamicSharedMemorySize, SMEM_BYTES);

  kde_normalize<<<NROWS / 4, 256, 0, stream>>>(X, Xn8, density, ticket);
  kde_gemm<<<dim3(NT, NSTRIP), 512, SMEM_BYTES, stream>>>(
      (const unsigned char*)ws, density, ticket, out);
}